// Round 14
// baseline (194.271 us; speedup 1.0000x reference)
//
#include <hip/hip_runtime.h>
#include <stdint.h>

#define NEAR_T  0.2f
#define SIG2MAX 9.0f
#define AMIN    (1.0f/255.0f)
#define NSL     8       // slices per sub-tile for the trace pass
#define TS      8       // trace sub-tile edge (8x8 = 64 px = one wave)
#define TB      16      // binning tile edge
#define KFIX    64      // fixed per-pixel key capacity (fast path)

__device__ __forceinline__ float dot3(float ax,float ay,float az,
                                      float bx,float by,float bz){
  return fmaf(ax,bx, fmaf(ay,by, az*bz));
}

__device__ __forceinline__ bool eval_hit(const float* __restrict__ gp,
    float rox,float roy,float roz, float rdx,float rdy,float rdz,
    float& t_out, float& a_out)
{
  float nx=gp[6], ny=gp[7], nz=gp[8];
  float den  = dot3(rdx,rdy,rdz, nx,ny,nz);
  float aden = fabsf(den);
  float num  = gp[11] - dot3(rox,roy,roz, nx,ny,nz);
  float sden = (aden < 1e-8f) ? 1e-8f : den;
  float t = __fdividef(num, sden);
  float ru = dot3(rox,roy,roz, gp[0],gp[1],gp[2]);
  float du = dot3(rdx,rdy,rdz, gp[0],gp[1],gp[2]);
  float u  = fmaf(t, du, ru - gp[9])  * gp[12];
  float rv = dot3(rox,roy,roz, gp[3],gp[4],gp[5]);
  float dv = dot3(rdx,rdy,rdz, gp[3],gp[4],gp[5]);
  float v  = fmaf(t, dv, rv - gp[10]) * gp[13];
  float r2 = fmaf(u,u, v*v);
  float G  = __expf(-0.5f*r2);
  float a  = fminf(gp[14]*G, 0.99f);
  t_out = t; a_out = a;
  return (t > NEAR_T) & (r2 < SIG2MAX) & (aden > 1e-8f) & (a > AMIN);
}

__device__ __forceinline__ unsigned long long make_key(float t, float a, uint32_t g){
  uint32_t a16 = (uint32_t)(a * 65535.f + 0.5f);
  return ((unsigned long long)__float_as_uint(t) << 32) |
         ((unsigned long long)a16 << 16) | (unsigned long long)g;
}

// pixel bbox from baux. Returns false if culled.
__device__ __forceinline__ bool pix_bbox(const float* __restrict__ bp,
    bool fallback, float axm, float bxm, float aym, float bym, int W, int H,
    int& x0, int& x1, int& y0, int& y1)
{
  if (fallback){ x0=0; x1=W-1; y0=0; y1=H-1; return true; }
  float mx=bp[0], my=bp[1], mz=bp[2], ex=bp[3], ey=bp[4], ez=bp[5];
  float zmin=mz-ez, zmax=mz+ez;
  if (zmax <= 0.16f) return false;
  if (zmin <= 1e-3f){ x0=0; x1=W-1; y0=0; y1=H-1; return true; }
  float xmin=mx-ex, xmax=mx+ex, ymin=my-ey, ymax=my+ey;
  float gxmin = (xmin>=0.f)? xmin/zmax : xmin/zmin;
  float gxmax = (xmax>=0.f)? xmax/zmin : xmax/zmax;
  float gymin = (ymin>=0.f)? ymin/zmax : ymin/zmin;
  float gymax = (ymax>=0.f)? ymax/zmin : ymax/zmax;
  float p0 = (gxmin - bxm)/axm, p1 = (gxmax - bxm)/axm;
  float q0 = (gymin - bym)/aym, q1 = (gymax - bym)/aym;
  int ix0 = (int)floorf(fminf(p0,p1)) - 1;
  int ix1 = (int)ceilf (fmaxf(p0,p1)) + 1;
  int iy0 = (int)floorf(fminf(q0,q1)) - 1;
  int iy1 = (int)ceilf (fmaxf(q0,q1)) + 1;
  if (ix1 < 0 || ix0 > W-1 || iy1 < 0 || iy0 > H-1) return false;
  x0 = max(ix0,0); x1 = min(ix1,W-1);
  y0 = max(iy0,0); y1 = min(iy1,H-1);
  return true;
}

// shared per-gaussian prep body
__device__ __forceinline__ void prep_one(int g, const float* __restrict__ rot,
    const float* __restrict__ means, const float* __restrict__ scales,
    const float* __restrict__ opac, const float* __restrict__ colors,
    float* __restrict__ geo, float* __restrict__ col, float* __restrict__ baux)
{
  float qw=rot[g*4+0], qx=rot[g*4+1], qy=rot[g*4+2], qz=rot[g*4+3];
  float n = sqrtf(qw*qw+qx*qx+qy*qy+qz*qz) + 1e-12f;
  qw/=n; qx/=n; qy/=n; qz/=n;
  float tux = 1.f-2.f*(qy*qy+qz*qz), tuy = 2.f*(qx*qy+qw*qz), tuz = 2.f*(qx*qz-qw*qy);
  float tvx = 2.f*(qx*qy-qw*qz), tvy = 1.f-2.f*(qx*qx+qz*qz), tvz = 2.f*(qy*qz+qw*qx);
  float nx  = 2.f*(qx*qz+qw*qy), ny  = 2.f*(qy*qz-qw*qx), nz  = 1.f-2.f*(qx*qx+qy*qy);
  float mx=means[g*3+0], my=means[g*3+1], mz=means[g*3+2];
  float sx=scales[g*2+0], sy=scales[g*2+1];
  float* gp = &geo[(size_t)g*16];
  gp[0]=tux; gp[1]=tuy; gp[2]=tuz;
  gp[3]=tvx; gp[4]=tvy; gp[5]=tvz;
  gp[6]=nx;  gp[7]=ny;  gp[8]=nz;
  gp[9]  = mx*tux+my*tuy+mz*tuz;
  gp[10] = mx*tvx+my*tvy+mz*tvz;
  gp[11] = mx*nx +my*ny +mz*nz;
  gp[12] = 1.f/sx;
  gp[13] = 1.f/sy;
  gp[14] = opac[g];
  gp[15] = 0.f;
  col[g*3+0]=colors[g*3+0]; col[g*3+1]=colors[g*3+1]; col[g*3+2]=colors[g*3+2];
  float* bp = &baux[(size_t)g*8];
  const float R3 = 3.02f;
  bp[0]=mx; bp[1]=my; bp[2]=mz;
  bp[3]=R3*(sx*fabsf(tux)+sy*fabsf(tvx));
  bp[4]=R3*(sx*fabsf(tuy)+sy*fabsf(tvy));
  bp[5]=R3*(sx*fabsf(tuz)+sy*fabsf(tvz));
  bp[6]=0.f; bp[7]=0.f;
}

// ---------------- kernel 1 (fast path): prep + check + zero + bbox + bin, 1 block
__global__ __launch_bounds__(1024)
void k_setup(const float* __restrict__ rot, const float* __restrict__ means,
             const float* __restrict__ scales, const float* __restrict__ opac,
             const float* __restrict__ colors, const float* __restrict__ ray_o,
             const float* __restrict__ ray_d,
             float* __restrict__ geo, float* __restrict__ col,
             float* __restrict__ baux, int4* __restrict__ bbox,
             uint32_t* __restrict__ cnt, uint32_t* __restrict__ tileLen,
             uint32_t* __restrict__ tileList,
             int P, int npix, int W, int H, int TXB, int TYB)
{
  __shared__ uint32_t sCnt[1024];
  __shared__ int sFB;
  int NTB = TXB*TYB;
  int tid = threadIdx.x;
  if (tid == 0) sFB = 0;
  for (int i=tid; i<NTB;  i+=1024) sCnt[i]=0u;
  for (int i=tid; i<npix; i+=1024) cnt[i]=0u;
  // derive pinhole map (locally, every thread)
  float g0x = ray_d[0]/ray_d[2], g0y = ray_d[1]/ray_d[2];
  float axm = ray_d[3]/ray_d[5] - g0x;
  float aym = ray_d[(size_t)W*3+1]/ray_d[(size_t)W*3+2] - g0y;
  if (!(fabsf(axm) > 1e-12f) || !(fabsf(aym) > 1e-12f)) sFB = 1;
  // per-gaussian prep
  for (int g=tid; g<P; g+=1024)
    prep_one(g, rot, means, scales, opac, colors, geo, col, baux);
  // full-image pinhole check
  for (int px=tid; px<npix; px+=1024){
    int ix = px % W, iy = px / W;
    float rox=ray_o[px*3+0], roy=ray_o[px*3+1], roz=ray_o[px*3+2];
    float rdx=ray_d[px*3+0], rdy=ray_d[px*3+1], rdz=ray_d[px*3+2];
    bool ok = (rox==0.f) & (roy==0.f) & (roz==0.f) & (rdz > 0.8f);
    if (ok){
      float gx = rdx/rdz, gy = rdy/rdz;
      ok = (fabsf(gx - fmaf(axm,(float)ix,g0x)) <= 3e-4f) &
           (fabsf(gy - fmaf(aym,(float)iy,g0y)) <= 3e-4f);
    }
    if (!ok) sFB = 1;
  }
  __syncthreads();            // baux visible (same CU), sFB final, sCnt zeroed
  bool fb = (sFB != 0);
  // bbox + single-pass bin (fixed-capacity per-tile segments)
  for (int g=tid; g<P; g+=1024){
    int x0,x1,y0,y1;
    bool ok = pix_bbox(&baux[(size_t)g*8], fb, axm,g0x,aym,g0y, W,H, x0,x1,y0,y1);
    bbox[g] = ok ? make_int4(x0,x1,y0,y1) : make_int4(1,0,1,0);
    if (!ok) continue;
    int tx0=x0/TB, tx1=x1/TB, ty0=y0/TB, ty1=y1/TB;
    for (int ty=ty0; ty<=ty1; ++ty)
      for (int tx=tx0; tx<=tx1; ++tx){
        int t = ty*TXB+tx;
        uint32_t slot = atomicAdd(&sCnt[t], 1u);
        tileList[(size_t)t*P + slot] = (uint32_t)g;
      }
  }
  __syncthreads();
  for (int i=tid; i<NTB; i+=1024) tileLen[i] = sCnt[i];
}

// ---------------- fallback (NTB > 1024): grid kernels + memset path ------------
__global__ void k_prep(const float* __restrict__ rot, const float* __restrict__ means,
                       const float* __restrict__ scales, const float* __restrict__ opac,
                       const float* __restrict__ colors, const float* __restrict__ ray_o,
                       const float* __restrict__ ray_d,
                       float* __restrict__ geo, float* __restrict__ col,
                       float* __restrict__ baux, uint32_t* __restrict__ misc,
                       int P, int npix, int W)
{
  int tid = blockIdx.x*blockDim.x + threadIdx.x;
  float g0x = ray_d[0]/ray_d[2], g0y = ray_d[1]/ray_d[2];
  float axm = ray_d[3]/ray_d[5] - g0x;
  float aym = ray_d[(size_t)W*3+1]/ray_d[(size_t)W*3+2] - g0y;
  if (tid == 0){
    float* mf = (float*)misc;
    mf[1] = axm; mf[2] = g0x; mf[3] = aym; mf[4] = g0y;
    if (!(fabsf(axm) > 1e-12f) || !(fabsf(aym) > 1e-12f)) atomicOr(misc, 1u);
  }
  if (tid < npix){
    int ix = tid % W, iy = tid / W;
    float rox=ray_o[tid*3+0], roy=ray_o[tid*3+1], roz=ray_o[tid*3+2];
    float rdx=ray_d[tid*3+0], rdy=ray_d[tid*3+1], rdz=ray_d[tid*3+2];
    bool ok = (rox==0.f) & (roy==0.f) & (roz==0.f) & (rdz > 0.8f);
    if (ok){
      float gx = rdx/rdz, gy = rdy/rdz;
      ok = (fabsf(gx - fmaf(axm,(float)ix,g0x)) <= 3e-4f) &
           (fabsf(gy - fmaf(aym,(float)iy,g0y)) <= 3e-4f);
    }
    if (!ok) atomicOr(misc, 1u);
  }
  if (tid < P)
    prep_one(tid, rot, means, scales, opac, colors, geo, col, baux);
}

__global__ void k_bbox(const float* __restrict__ baux, const uint32_t* __restrict__ misc,
                       int4* __restrict__ bbox, int P, int W, int H)
{
  int g = blockIdx.x*blockDim.x + threadIdx.x;
  if (g >= P) return;
  const float* mf = (const float*)misc;
  bool fb = (misc[0] != 0u);
  int x0,x1,y0,y1;
  bool ok = pix_bbox(&baux[(size_t)g*8], fb, mf[1],mf[2],mf[3],mf[4], W,H, x0,x1,y0,y1);
  bbox[g] = ok ? make_int4(x0,x1,y0,y1) : make_int4(1,0,1,0);
}

__global__ void k_bin_global(const int4* __restrict__ bbox, uint32_t* __restrict__ tileLen,
                             uint32_t* __restrict__ tileList, int P, int TXB)
{
  int g = blockIdx.x*blockDim.x + threadIdx.x;
  if (g >= P) return;
  int4 bb = bbox[g];
  if (bb.x > bb.y) return;
  int tx0=bb.x/TB, tx1=bb.y/TB, ty0=bb.z/TB, ty1=bb.w/TB;
  for (int ty=ty0; ty<=ty1; ++ty)
    for (int tx=tx0; tx<=tx1; ++tx){
      int t = ty*TXB+tx;
      uint32_t slot = atomicAdd(&tileLen[t], 1u);
      tileList[(size_t)t*P + slot] = (uint32_t)g;
    }
}

// ---------------- kernel 2: trace, one wave per 8x8 sub-tile slice -------------
__global__ __launch_bounds__(64)
void k_trace(const float* __restrict__ geo, const int4* __restrict__ bbox,
             const float* __restrict__ ray_o, const float* __restrict__ ray_d,
             const uint32_t* __restrict__ tileLen, const uint32_t* __restrict__ tileList,
             uint32_t* __restrict__ cnt, unsigned long long* __restrict__ keys64,
             int W, int H, int TXB, int STX, int P)
{
  int st = blockIdx.x;
  int stx = st % STX, sty = st / STX;
  int lane = threadIdx.x;
  int ix = stx*TS + (lane & (TS-1));
  int iy = sty*TS + (lane / TS);
  bool live = (ix < W) & (iy < H);
  int px = live ? (iy*W + ix) : 0;
  int pt = (sty*TS/TB)*TXB + (stx*TS/TB);
  uint32_t base = (uint32_t)pt * (uint32_t)P;
  uint32_t len  = tileLen[pt];
  int sx0 = stx*TS, sx1 = sx0 + TS-1;
  int sy0 = sty*TS, sy1 = sy0 + TS-1;
  float rox=ray_o[px*3+0], roy=ray_o[px*3+1], roz=ray_o[px*3+2];
  float rdx=ray_d[px*3+0], rdy=ray_d[px*3+1], rdz=ray_d[px*3+2];
  for (uint32_t s = blockIdx.y; s < len; s += NSL){
    int gu = __builtin_amdgcn_readfirstlane((int)tileList[base+s]);
    int4 bb = bbox[gu];
    if (bb.x > sx1 || bb.y < sx0 || bb.z > sy1 || bb.w < sy0) continue;  // uniform skip
    const float* gp = &geo[(size_t)gu*16];
    float t,a;
    bool hit = eval_hit(gp, rox,roy,roz, rdx,rdy,rdz, t, a) && live;
    if (hit){
      uint32_t slot = atomicAdd(&cnt[px], 1u);
      if (slot < KFIX) keys64[(size_t)px*KFIX + slot] = make_key(t, a, (uint32_t)gu);
    }
  }
}

// ---------------- composite helpers ----------------
__device__ __forceinline__ float wred(float v){
  #pragma unroll
  for (int d=32; d>0; d>>=1) v += __shfl_down(v, d);
  return v;
}

__device__ __forceinline__ void comp_write(int px, int npix, int lane,
    float r_, float g_, float bl_, float dpt_, float acc_,
    float nx_, float ny_, float nz_, const float* __restrict__ bg,
    float* __restrict__ out)
{
  r_ = wred(r_); g_ = wred(g_); bl_ = wred(bl_);
  dpt_ = wred(dpt_); acc_ = wred(acc_);
  nx_ = wred(nx_); ny_ = wred(ny_); nz_ = wred(nz_);
  if (lane == 0){
    float one_m = 1.f - acc_;
    out[(size_t)px*3+0] = r_  + one_m*bg[0];
    out[(size_t)px*3+1] = g_  + one_m*bg[1];
    out[(size_t)px*3+2] = bl_ + one_m*bg[2];
    out[(size_t)npix*3 + px] = dpt_;
    out[(size_t)npix*4 + px] = acc_;
    out[(size_t)npix*5 + (size_t)px*3+0] = nx_;
    out[(size_t)npix*5 + (size_t)px*3+1] = ny_;
    out[(size_t)npix*5 + (size_t)px*3+2] = nz_;
  }
}

// ---------------- kernel 3: composite all pixels with K<=KFIX ------------------
__global__ __launch_bounds__(256)
void k_comp_small(const unsigned long long* __restrict__ keys64,
                  const uint32_t* __restrict__ cnt,
                  const float* __restrict__ geo, const float* __restrict__ col,
                  const float* __restrict__ bg, float* __restrict__ out, int npix)
{
  int lane = threadIdx.x & 63;
  int wave = threadIdx.x >> 6;
  for (int px = (int)(blockIdx.x*4u + wave); px < npix; px += (int)(gridDim.x*4u)){
    uint32_t K = cnt[px];
    if (K > (uint32_t)KFIX) continue;      // overflow kernel handles
    unsigned long long key = (lane < (int)K) ? keys64[(size_t)px*KFIX + lane] : ~0ull;
    #pragma unroll
    for (int k=2; k<=64; k<<=1){
      #pragma unroll
      for (int j=k>>1; j>0; j>>=1){
        unsigned long long other = __shfl_xor(key, j);
        bool keep_min = (((lane & j) == 0) == ((lane & k) == 0));
        unsigned long long lo = key < other ? key : other;
        unsigned long long hi = key < other ? other : key;
        key = keep_min ? lo : hi;
      }
    }
    bool valid = lane < (int)K;
    const float inv65535 = 1.f/65535.f;
    float a = (float)((uint32_t)(key >> 16) & 0xFFFFu) * inv65535;
    float p = valid ? (1.f - a) : 1.f;
    float ip = p;
    #pragma unroll
    for (int d=1; d<64; d<<=1){ float v = __shfl_up(ip, d); if (lane >= d) ip *= v; }
    float T = __shfl_up(ip, 1);
    if (lane == 0) T = 1.f;
    float r_=0.f, g_=0.f, bl_=0.f, dpt_=0.f, acc_=0.f, nx_=0.f, ny_=0.f, nz_=0.f;
    if (valid){
      float t = __uint_as_float((uint32_t)(key >> 32));
      uint32_t g = (uint32_t)(key & 0xFFFFu);
      float w = a * T;
      const float* gp = &geo[(size_t)g*16];
      const float* cp = &col[(size_t)g*3];
      r_ = w*cp[0]; g_ = w*cp[1]; bl_ = w*cp[2];
      dpt_ = w*t; acc_ = w;
      nx_ = w*gp[6]; ny_ = w*gp[7]; nz_ = w*gp[8];
    }
    comp_write(px, npix, lane, r_,g_,bl_,dpt_,acc_,nx_,ny_,nz_, bg, out);
  }
}

// ---------------- kernel 4: overflow composite (K>KFIX) — re-trace into LDS -----
__global__ __launch_bounds__(64)
void k_comp_over(const float* __restrict__ geo, const int4* __restrict__ bbox,
                 const float* __restrict__ col,
                 const float* __restrict__ ray_o, const float* __restrict__ ray_d,
                 const uint32_t* __restrict__ tileLen, const uint32_t* __restrict__ tileList,
                 const uint32_t* __restrict__ cnt, const float* __restrict__ bg,
                 float* __restrict__ out, int npix, int W, int TXB, int P)
{
  __shared__ unsigned long long sk[4096];
  int lane = threadIdx.x;
  unsigned long long lt = (1ull << lane) - 1ull;
  for (int px = (int)blockIdx.x; px < npix; px += (int)gridDim.x){
    if (cnt[px] <= (uint32_t)KFIX) continue;
    int ix = px % W, iy = px / W;
    int pt = (iy/TB)*TXB + (ix/TB);
    uint32_t base = (uint32_t)pt * (uint32_t)P;
    uint32_t len  = tileLen[pt];
    float rox=ray_o[px*3+0], roy=ray_o[px*3+1], roz=ray_o[px*3+2];
    float rdx=ray_d[px*3+0], rdy=ray_d[px*3+1], rdz=ray_d[px*3+2];

    uint32_t run = 0;
    for (uint32_t s0=0; s0<len; s0+=64){
      uint32_t s = s0 + (uint32_t)lane;
      bool act = s < len;
      uint32_t gu = act ? tileList[base+s] : 0u;
      float t=0.f, a=0.f;
      bool hit = false;
      if (act){
        int4 bb = bbox[gu];
        if (bb.x <= ix && ix <= bb.y && bb.z <= iy && iy <= bb.w)
          hit = eval_hit(&geo[(size_t)gu*16], rox,roy,roz, rdx,rdy,rdz, t, a);
      }
      unsigned long long m = __ballot(hit);
      if (hit){
        uint32_t slot = run + (uint32_t)__popcll(m & lt);
        if (slot < 4096u) sk[slot] = make_key(t, a, gu);
      }
      run += (uint32_t)__popcll(m);
    }
    uint32_t K = min(run, 4096u);
    uint32_t N = 1; while (N < K) N <<= 1;
    for (uint32_t i=K+lane; i<N; i+=64) sk[i] = ~0ull;
    __syncthreads();

    for (uint32_t kk=2; kk<=N; kk<<=1){
      for (uint32_t j=kk>>1; j>0; j>>=1){
        for (uint32_t i=lane; i<N; i+=64){
          uint32_t ij = i ^ j;
          if (ij > i){
            unsigned long long a = sk[i], b = sk[ij];
            bool up = ((i & kk) == 0);
            if ((a > b) == up){ sk[i] = b; sk[ij] = a; }
          }
        }
        __syncthreads();
      }
    }

    const float inv65535 = 1.f/65535.f;
    uint32_t C = (K + 63) >> 6;
    uint32_t b0 = lane*C, e0 = min(b0 + C, K);
    float p = 1.f;
    for (uint32_t i=b0; i<e0; ++i){
      float a = (float)((uint32_t)(sk[i] >> 16) & 0xFFFFu) * inv65535;
      p *= (1.f - a);
    }
    float ip = p;
    #pragma unroll
    for (int d=1; d<64; d<<=1){ float v = __shfl_up(ip, d); if (lane >= d) ip *= v; }
    float T = __shfl_up(ip, 1);
    if (lane == 0) T = 1.f;

    float r_=0.f, g_=0.f, bl_=0.f, dpt_=0.f, acc_=0.f, nx_=0.f, ny_=0.f, nz_=0.f;
    for (uint32_t i=b0; i<e0; ++i){
      unsigned long long key = sk[i];
      float t = __uint_as_float((uint32_t)(key >> 32));
      float a = (float)((uint32_t)(key >> 16) & 0xFFFFu) * inv65535;
      uint32_t g = (uint32_t)(key & 0xFFFFu);
      float w = a * T;
      const float* gp = &geo[(size_t)g*16];
      const float* cp = &col[(size_t)g*3];
      r_  += w * cp[0]; g_ += w * cp[1]; bl_ += w * cp[2];
      dpt_ += w * t; acc_ += w;
      nx_ += w * gp[6]; ny_ += w * gp[7]; nz_ += w * gp[8];
      T *= (1.f - a);
    }
    comp_write(px, npix, lane, r_,g_,bl_,dpt_,acc_,nx_,ny_,nz_, bg, out);
    __syncthreads();   // protect sk reuse on next grid-stride iteration
  }
}

// ---------------- host launcher ----------------
extern "C" void kernel_launch(void* const* d_in, const int* in_sizes, int n_in,
                              void* d_out, int out_size, void* d_ws, size_t ws_size,
                              hipStream_t stream)
{
  const float* ray_o  = (const float*)d_in[0];
  const float* ray_d  = (const float*)d_in[1];
  const float* means  = (const float*)d_in[2];
  const float* scales = (const float*)d_in[3];
  const float* rot    = (const float*)d_in[4];
  const float* opac   = (const float*)d_in[5];
  const float* colors = (const float*)d_in[6];
  const float* bg     = (const float*)d_in[7];
  float* out = (float*)d_out;

  int npix = in_sizes[0] / 3;     // 16384
  int P    = in_sizes[2] / 3;     // 4096
  int W    = (int)(sqrtf((float)npix) + 0.5f);   // square image (reference H=W)
  int H    = npix / W;
  int TXB  = (W + TB - 1) / TB;
  int TYB  = (H + TB - 1) / TB;
  int NTB  = TXB * TYB;          // 64 for 128x128
  int STX  = (W + TS - 1) / TS;
  int STY  = (H + TS - 1) / TS;
  int NST  = STX * STY;          // 256 for 128x128

  uint8_t* ws = (uint8_t*)d_ws;
  size_t o_geo   = 0;
  size_t sz_geo  = ((size_t)P*16*4 + 255) & ~(size_t)255;
  size_t o_col   = o_geo + sz_geo;
  size_t sz_col  = ((size_t)P*3*4 + 255) & ~(size_t)255;
  size_t o_baux  = o_col + sz_col;
  size_t sz_baux = ((size_t)P*8*4 + 255) & ~(size_t)255;
  size_t o_bbox  = o_baux + sz_baux;
  size_t sz_bbox = ((size_t)P*16 + 255) & ~(size_t)255;

  // control region (memset only on fallback path): cnt | tileLen | misc
  size_t o_ctrl  = o_bbox + sz_bbox;
  size_t sz_pix  = ((size_t)npix*4 + 255) & ~(size_t)255;
  size_t o_cnt   = o_ctrl;
  size_t sz_ntb  = ((size_t)NTB*4 + 255) & ~(size_t)255;
  size_t o_tlen  = o_cnt + sz_pix;
  size_t o_misc  = o_tlen + sz_ntb;
  size_t ctrl_sz = (o_misc + 256) - o_ctrl;

  size_t o_tlist = o_ctrl + ctrl_sz;
  size_t sz_tlist= (((size_t)NTB*(size_t)P*4) + 255) & ~(size_t)255;  // 1 MB @128
  size_t o_k64   = o_tlist + sz_tlist;                                // 8 MB

  float*    geo     = (float*)(ws + o_geo);
  float*    col     = (float*)(ws + o_col);
  float*    baux    = (float*)(ws + o_baux);
  int4*     bbox    = (int4*)(ws + o_bbox);
  uint32_t* cnt     = (uint32_t*)(ws + o_cnt);
  uint32_t* tileLen = (uint32_t*)(ws + o_tlen);
  uint32_t* misc    = (uint32_t*)(ws + o_misc);
  uint32_t* tileList= (uint32_t*)(ws + o_tlist);
  unsigned long long* keys64 = (unsigned long long*)(ws + o_k64);

  if (NTB <= 1024){
    // fully fused setup: no memset, no misc round-trip, 1 dispatch
    k_setup<<<1, 1024, 0, stream>>>(rot, means, scales, opac, colors, ray_o, ray_d,
                                    geo, col, baux, bbox, cnt, tileLen, tileList,
                                    P, npix, W, H, TXB, TYB);
  } else {
    hipMemsetAsync(ws + o_ctrl, 0, ctrl_sz, stream);
    int initN = npix > P ? npix : P;
    k_prep<<<(initN + 255)/256, 256, 0, stream>>>(rot, means, scales, opac, colors,
                                                  ray_o, ray_d, geo, col, baux, misc,
                                                  P, npix, W);
    k_bbox<<<(P + 255)/256, 256, 0, stream>>>(baux, misc, bbox, P, W, H);
    k_bin_global<<<(P + 255)/256, 256, 0, stream>>>(bbox, tileLen, tileList, P, TXB);
  }
  dim3 tgrid(NST, NSL);
  k_trace<<<tgrid, 64, 0, stream>>>(geo, bbox, ray_o, ray_d, tileLen, tileList,
                                    cnt, keys64, W, H, TXB, STX, P);
  k_comp_small<<<1024, 256, 0, stream>>>(keys64, cnt, geo, col, bg, out, npix);
  k_comp_over<<<1024, 64, 0, stream>>>(geo, bbox, col, ray_o, ray_d, tileLen, tileList,
                                       cnt, bg, out, npix, W, TXB, P);
}

// Round 15
// 132.642 us; speedup vs baseline: 1.4646x; 1.4646x over previous
//
#include <hip/hip_runtime.h>
#include <stdint.h>

#define NEAR_T  0.2f
#define SIG2MAX 9.0f
#define AMIN    (1.0f/255.0f)
#define NSL     8       // slices per sub-tile for the trace pass
#define TS      8       // trace sub-tile edge (8x8 = 64 px = one wave)
#define TB      16      // binning tile edge
#define KFIX    64      // fixed per-pixel key capacity (fast path)

__device__ __forceinline__ float dot3(float ax,float ay,float az,
                                      float bx,float by,float bz){
  return fmaf(ax,bx, fmaf(ay,by, az*bz));
}

__device__ __forceinline__ bool eval_hit(const float* __restrict__ gp,
    float rox,float roy,float roz, float rdx,float rdy,float rdz,
    float& t_out, float& a_out)
{
  float nx=gp[6], ny=gp[7], nz=gp[8];
  float den  = dot3(rdx,rdy,rdz, nx,ny,nz);
  float aden = fabsf(den);
  float num  = gp[11] - dot3(rox,roy,roz, nx,ny,nz);
  float sden = (aden < 1e-8f) ? 1e-8f : den;
  float t = __fdividef(num, sden);
  float ru = dot3(rox,roy,roz, gp[0],gp[1],gp[2]);
  float du = dot3(rdx,rdy,rdz, gp[0],gp[1],gp[2]);
  float u  = fmaf(t, du, ru - gp[9])  * gp[12];
  float rv = dot3(rox,roy,roz, gp[3],gp[4],gp[5]);
  float dv = dot3(rdx,rdy,rdz, gp[3],gp[4],gp[5]);
  float v  = fmaf(t, dv, rv - gp[10]) * gp[13];
  float r2 = fmaf(u,u, v*v);
  float G  = __expf(-0.5f*r2);
  float a  = fminf(gp[14]*G, 0.99f);
  t_out = t; a_out = a;
  return (t > NEAR_T) & (r2 < SIG2MAX) & (aden > 1e-8f) & (a > AMIN);
}

__device__ __forceinline__ unsigned long long make_key(float t, float a, uint32_t g){
  uint32_t a16 = (uint32_t)(a * 65535.f + 0.5f);
  return ((unsigned long long)__float_as_uint(t) << 32) |
         ((unsigned long long)a16 << 16) | (unsigned long long)g;
}

// pixel bbox from values (assumes pinhole map valid). Returns false if culled.
__device__ __forceinline__ bool pix_bbox_vals(
    float mx, float my, float mz, float ex, float ey, float ez,
    float axm, float bxm, float aym, float bym, int W, int H,
    int& x0, int& x1, int& y0, int& y1)
{
  float zmin=mz-ez, zmax=mz+ez;
  if (zmax <= 0.16f) return false;
  if (zmin <= 1e-3f){ x0=0; x1=W-1; y0=0; y1=H-1; return true; }
  float xmin=mx-ex, xmax=mx+ex, ymin=my-ey, ymax=my+ey;
  float gxmin = (xmin>=0.f)? xmin/zmax : xmin/zmin;
  float gxmax = (xmax>=0.f)? xmax/zmin : xmax/zmax;
  float gymin = (ymin>=0.f)? ymin/zmax : ymin/zmin;
  float gymax = (ymax>=0.f)? ymax/zmin : ymax/zmax;
  float p0 = (gxmin - bxm)/axm, p1 = (gxmax - bxm)/axm;
  float q0 = (gymin - bym)/aym, q1 = (gymax - bym)/aym;
  int ix0 = (int)floorf(fminf(p0,p1)) - 1;
  int ix1 = (int)ceilf (fmaxf(p0,p1)) + 1;
  int iy0 = (int)floorf(fminf(q0,q1)) - 1;
  int iy1 = (int)ceilf (fmaxf(q0,q1)) + 1;
  if (ix1 < 0 || ix0 > W-1 || iy1 < 0 || iy0 > H-1) return false;
  x0 = max(ix0,0); x1 = min(ix1,W-1);
  y0 = max(iy0,0); y1 = min(iy1,H-1);
  return true;
}

// ---------------- kernel 1: grid-wide prep + check + zero + bbox ----------------
// Flag protocol: every block writes badArr[blockIdx] unconditionally (no init).
__global__ __launch_bounds__(256)
void k_prep(const float* __restrict__ rot, const float* __restrict__ means,
            const float* __restrict__ scales, const float* __restrict__ opac,
            const float* __restrict__ colors, const float* __restrict__ ray_o,
            const float* __restrict__ ray_d,
            float* __restrict__ geo, float* __restrict__ col,
            int4* __restrict__ bbox, uint32_t* __restrict__ cnt,
            uint32_t* __restrict__ badArr, int P, int npix, int W, int H)
{
  __shared__ int sBad;
  int lt = threadIdx.x;
  if (lt == 0) sBad = 0;
  __syncthreads();
  int tid = blockIdx.x*blockDim.x + lt;
  // derive linear pixel->screen map (locally; identical across threads)
  float g0x = ray_d[0]/ray_d[2], g0y = ray_d[1]/ray_d[2];
  float axm = ray_d[3]/ray_d[5] - g0x;
  float aym = ray_d[(size_t)W*3+1]/ray_d[(size_t)W*3+2] - g0y;
  bool mapok = (fabsf(axm) > 1e-12f) && (fabsf(aym) > 1e-12f);
  if (!mapok) sBad = 1;
  if (tid < npix){
    cnt[tid] = 0u;
    int ix = tid % W, iy = tid / W;
    float rox=ray_o[tid*3+0], roy=ray_o[tid*3+1], roz=ray_o[tid*3+2];
    float rdx=ray_d[tid*3+0], rdy=ray_d[tid*3+1], rdz=ray_d[tid*3+2];
    bool ok = (rox==0.f) & (roy==0.f) & (roz==0.f) & (rdz > 0.8f);
    if (ok && mapok){
      float gx = rdx/rdz, gy = rdy/rdz;
      ok = (fabsf(gx - fmaf(axm,(float)ix,g0x)) <= 3e-4f) &
           (fabsf(gy - fmaf(aym,(float)iy,g0y)) <= 3e-4f);
    }
    if (!ok) sBad = 1;
  }
  if (tid < P){
    int g = tid;
    float qw=rot[g*4+0], qx=rot[g*4+1], qy=rot[g*4+2], qz=rot[g*4+3];
    float n = sqrtf(qw*qw+qx*qx+qy*qy+qz*qz) + 1e-12f;
    qw/=n; qx/=n; qy/=n; qz/=n;
    float tux = 1.f-2.f*(qy*qy+qz*qz), tuy = 2.f*(qx*qy+qw*qz), tuz = 2.f*(qx*qz-qw*qy);
    float tvx = 2.f*(qx*qy-qw*qz), tvy = 1.f-2.f*(qx*qx+qz*qz), tvz = 2.f*(qy*qz+qw*qx);
    float nx  = 2.f*(qx*qz+qw*qy), ny  = 2.f*(qy*qz-qw*qx), nz  = 1.f-2.f*(qx*qx+qy*qy);
    float mx=means[g*3+0], my=means[g*3+1], mz=means[g*3+2];
    float sx=scales[g*2+0], sy=scales[g*2+1];
    float* gp = &geo[(size_t)g*16];
    gp[0]=tux; gp[1]=tuy; gp[2]=tuz;
    gp[3]=tvx; gp[4]=tvy; gp[5]=tvz;
    gp[6]=nx;  gp[7]=ny;  gp[8]=nz;
    gp[9]  = mx*tux+my*tuy+mz*tuz;
    gp[10] = mx*tvx+my*tvy+mz*tvz;
    gp[11] = mx*nx +my*ny +mz*nz;
    gp[12] = 1.f/sx;
    gp[13] = 1.f/sy;
    gp[14] = opac[g];
    gp[15] = 0.f;
    col[g*3+0]=colors[g*3+0]; col[g*3+1]=colors[g*3+1]; col[g*3+2]=colors[g*3+2];
    const float R3 = 3.02f;
    float ex = R3*(sx*fabsf(tux)+sy*fabsf(tvx));
    float ey = R3*(sx*fabsf(tuy)+sy*fabsf(tvy));
    float ez = R3*(sx*fabsf(tuz)+sy*fabsf(tvz));
    int x0,x1,y0,y1;
    bool ok = mapok && pix_bbox_vals(mx,my,mz, ex,ey,ez, axm,g0x,aym,g0y, W,H,
                                     x0,x1,y0,y1);
    bbox[g] = ok ? make_int4(x0,x1,y0,y1) : make_int4(1,0,1,0);
  }
  __syncthreads();
  if (lt == 0) badArr[blockIdx.x] = (uint32_t)sBad;
}

// ---------------- kernel 2: single-block bin (fb resolve + LDS-atomic fill) -----
__global__ __launch_bounds__(1024)
void k_bin(int4* __restrict__ bbox, uint32_t* __restrict__ tileLen,
           uint32_t* __restrict__ tileList, const uint32_t* __restrict__ badArr,
           int nb, int P, int W, int H, int TXB, int TYB)
{
  __shared__ uint32_t sCnt[1024];
  __shared__ int sFB;
  int NTB = TXB*TYB;
  int tid = threadIdx.x;
  if (tid == 0) sFB = 0;
  for (int i=tid; i<NTB; i+=1024) sCnt[i]=0u;
  __syncthreads();
  if (tid < nb && badArr[tid] != 0u) sFB = 1;
  __syncthreads();
  if (sFB){                       // rare fallback: fullscreen bbox for all
    for (int g=tid; g<P; g+=1024) bbox[g] = make_int4(0,W-1,0,H-1);
    __syncthreads();
  }
  for (int g=tid; g<P; g+=1024){
    int4 bb = bbox[g];
    if (bb.x > bb.y) continue;
    int tx0=bb.x/TB, tx1=bb.y/TB, ty0=bb.z/TB, ty1=bb.w/TB;
    for (int ty=ty0; ty<=ty1; ++ty)
      for (int tx=tx0; tx<=tx1; ++tx){
        int t = ty*TXB+tx;
        uint32_t slot = atomicAdd(&sCnt[t], 1u);
        tileList[(size_t)t*P + slot] = (uint32_t)g;
      }
  }
  __syncthreads();
  for (int i=tid; i<NTB; i+=1024) tileLen[i] = sCnt[i];
}

// ---------------- fallback (NTB > 1024): fb-fix + memset + global-atomic bin ----
__global__ __launch_bounds__(1024)
void k_fbfix(int4* __restrict__ bbox, const uint32_t* __restrict__ badArr,
             int nb, int P, int W, int H)
{
  __shared__ int sFB;
  int tid = threadIdx.x;
  if (tid == 0) sFB = 0;
  __syncthreads();
  if (tid < nb && badArr[tid] != 0u) sFB = 1;
  __syncthreads();
  if (sFB)
    for (int g=tid; g<P; g+=1024) bbox[g] = make_int4(0,W-1,0,H-1);
}

__global__ void k_bin_global(const int4* __restrict__ bbox, uint32_t* __restrict__ tileLen,
                             uint32_t* __restrict__ tileList, int P, int TXB)
{
  int g = blockIdx.x*blockDim.x + threadIdx.x;
  if (g >= P) return;
  int4 bb = bbox[g];
  if (bb.x > bb.y) return;
  int tx0=bb.x/TB, tx1=bb.y/TB, ty0=bb.z/TB, ty1=bb.w/TB;
  for (int ty=ty0; ty<=ty1; ++ty)
    for (int tx=tx0; tx<=tx1; ++tx){
      int t = ty*TXB+tx;
      uint32_t slot = atomicAdd(&tileLen[t], 1u);
      tileList[(size_t)t*P + slot] = (uint32_t)g;
    }
}

// ---------------- kernel 3: trace, one wave per 8x8 sub-tile slice -------------
__global__ __launch_bounds__(64)
void k_trace(const float* __restrict__ geo, const int4* __restrict__ bbox,
             const float* __restrict__ ray_o, const float* __restrict__ ray_d,
             const uint32_t* __restrict__ tileLen, const uint32_t* __restrict__ tileList,
             uint32_t* __restrict__ cnt, unsigned long long* __restrict__ keys64,
             int W, int H, int TXB, int STX, int P)
{
  int st = blockIdx.x;
  int stx = st % STX, sty = st / STX;
  int lane = threadIdx.x;
  int ix = stx*TS + (lane & (TS-1));
  int iy = sty*TS + (lane / TS);
  bool live = (ix < W) & (iy < H);
  int px = live ? (iy*W + ix) : 0;
  int pt = (sty*TS/TB)*TXB + (stx*TS/TB);
  uint32_t base = (uint32_t)pt * (uint32_t)P;
  uint32_t len  = tileLen[pt];
  int sx0 = stx*TS, sx1 = sx0 + TS-1;
  int sy0 = sty*TS, sy1 = sy0 + TS-1;
  float rox=ray_o[px*3+0], roy=ray_o[px*3+1], roz=ray_o[px*3+2];
  float rdx=ray_d[px*3+0], rdy=ray_d[px*3+1], rdz=ray_d[px*3+2];
  for (uint32_t s = blockIdx.y; s < len; s += NSL){
    int gu = __builtin_amdgcn_readfirstlane((int)tileList[base+s]);
    int4 bb = bbox[gu];
    if (bb.x > sx1 || bb.y < sx0 || bb.z > sy1 || bb.w < sy0) continue;  // uniform skip
    const float* gp = &geo[(size_t)gu*16];
    float t,a;
    bool hit = eval_hit(gp, rox,roy,roz, rdx,rdy,rdz, t, a) && live;
    if (hit){
      uint32_t slot = atomicAdd(&cnt[px], 1u);
      if (slot < KFIX) keys64[(size_t)px*KFIX + slot] = make_key(t, a, (uint32_t)gu);
    }
  }
}

// ---------------- composite helpers ----------------
__device__ __forceinline__ float wred(float v){
  #pragma unroll
  for (int d=32; d>0; d>>=1) v += __shfl_down(v, d);
  return v;
}

__device__ __forceinline__ void comp_write(int px, int npix, int lane,
    float r_, float g_, float bl_, float dpt_, float acc_,
    float nx_, float ny_, float nz_, const float* __restrict__ bg,
    float* __restrict__ out)
{
  r_ = wred(r_); g_ = wred(g_); bl_ = wred(bl_);
  dpt_ = wred(dpt_); acc_ = wred(acc_);
  nx_ = wred(nx_); ny_ = wred(ny_); nz_ = wred(nz_);
  if (lane == 0){
    float one_m = 1.f - acc_;
    out[(size_t)px*3+0] = r_  + one_m*bg[0];
    out[(size_t)px*3+1] = g_  + one_m*bg[1];
    out[(size_t)px*3+2] = bl_ + one_m*bg[2];
    out[(size_t)npix*3 + px] = dpt_;
    out[(size_t)npix*4 + px] = acc_;
    out[(size_t)npix*5 + (size_t)px*3+0] = nx_;
    out[(size_t)npix*5 + (size_t)px*3+1] = ny_;
    out[(size_t)npix*5 + (size_t)px*3+2] = nz_;
  }
}

// ---------------- kernel 4: composite all pixels with K<=KFIX ------------------
__global__ __launch_bounds__(256)
void k_comp_small(const unsigned long long* __restrict__ keys64,
                  const uint32_t* __restrict__ cnt,
                  const float* __restrict__ geo, const float* __restrict__ col,
                  const float* __restrict__ bg, float* __restrict__ out, int npix)
{
  int lane = threadIdx.x & 63;
  int wave = threadIdx.x >> 6;
  for (int px = (int)(blockIdx.x*4u + wave); px < npix; px += (int)(gridDim.x*4u)){
    uint32_t K = cnt[px];
    if (K > (uint32_t)KFIX) continue;      // overflow kernel handles
    unsigned long long key = (lane < (int)K) ? keys64[(size_t)px*KFIX + lane] : ~0ull;
    #pragma unroll
    for (int k=2; k<=64; k<<=1){
      #pragma unroll
      for (int j=k>>1; j>0; j>>=1){
        unsigned long long other = __shfl_xor(key, j);
        bool keep_min = (((lane & j) == 0) == ((lane & k) == 0));
        unsigned long long lo = key < other ? key : other;
        unsigned long long hi = key < other ? other : key;
        key = keep_min ? lo : hi;
      }
    }
    bool valid = lane < (int)K;
    const float inv65535 = 1.f/65535.f;
    float a = (float)((uint32_t)(key >> 16) & 0xFFFFu) * inv65535;
    float p = valid ? (1.f - a) : 1.f;
    float ip = p;
    #pragma unroll
    for (int d=1; d<64; d<<=1){ float v = __shfl_up(ip, d); if (lane >= d) ip *= v; }
    float T = __shfl_up(ip, 1);
    if (lane == 0) T = 1.f;
    float r_=0.f, g_=0.f, bl_=0.f, dpt_=0.f, acc_=0.f, nx_=0.f, ny_=0.f, nz_=0.f;
    if (valid){
      float t = __uint_as_float((uint32_t)(key >> 32));
      uint32_t g = (uint32_t)(key & 0xFFFFu);
      float w = a * T;
      const float* gp = &geo[(size_t)g*16];
      const float* cp = &col[(size_t)g*3];
      r_ = w*cp[0]; g_ = w*cp[1]; bl_ = w*cp[2];
      dpt_ = w*t; acc_ = w;
      nx_ = w*gp[6]; ny_ = w*gp[7]; nz_ = w*gp[8];
    }
    comp_write(px, npix, lane, r_,g_,bl_,dpt_,acc_,nx_,ny_,nz_, bg, out);
  }
}

// ---------------- kernel 5: overflow composite (K>KFIX) — re-trace into LDS -----
__global__ __launch_bounds__(64)
void k_comp_over(const float* __restrict__ geo, const int4* __restrict__ bbox,
                 const float* __restrict__ col,
                 const float* __restrict__ ray_o, const float* __restrict__ ray_d,
                 const uint32_t* __restrict__ tileLen, const uint32_t* __restrict__ tileList,
                 const uint32_t* __restrict__ cnt, const float* __restrict__ bg,
                 float* __restrict__ out, int npix, int W, int TXB, int P)
{
  __shared__ unsigned long long sk[4096];
  int lane = threadIdx.x;
  unsigned long long lt = (1ull << lane) - 1ull;
  for (int px = (int)blockIdx.x; px < npix; px += (int)gridDim.x){
    if (cnt[px] <= (uint32_t)KFIX) continue;
    int ix = px % W, iy = px / W;
    int pt = (iy/TB)*TXB + (ix/TB);
    uint32_t base = (uint32_t)pt * (uint32_t)P;
    uint32_t len  = tileLen[pt];
    float rox=ray_o[px*3+0], roy=ray_o[px*3+1], roz=ray_o[px*3+2];
    float rdx=ray_d[px*3+0], rdy=ray_d[px*3+1], rdz=ray_d[px*3+2];

    uint32_t run = 0;
    for (uint32_t s0=0; s0<len; s0+=64){
      uint32_t s = s0 + (uint32_t)lane;
      bool act = s < len;
      uint32_t gu = act ? tileList[base+s] : 0u;
      float t=0.f, a=0.f;
      bool hit = false;
      if (act){
        int4 bb = bbox[gu];
        if (bb.x <= ix && ix <= bb.y && bb.z <= iy && iy <= bb.w)
          hit = eval_hit(&geo[(size_t)gu*16], rox,roy,roz, rdx,rdy,rdz, t, a);
      }
      unsigned long long m = __ballot(hit);
      if (hit){
        uint32_t slot = run + (uint32_t)__popcll(m & lt);
        if (slot < 4096u) sk[slot] = make_key(t, a, gu);
      }
      run += (uint32_t)__popcll(m);
    }
    uint32_t K = min(run, 4096u);
    uint32_t N = 1; while (N < K) N <<= 1;
    for (uint32_t i=K+lane; i<N; i+=64) sk[i] = ~0ull;
    __syncthreads();

    for (uint32_t kk=2; kk<=N; kk<<=1){
      for (uint32_t j=kk>>1; j>0; j>>=1){
        for (uint32_t i=lane; i<N; i+=64){
          uint32_t ij = i ^ j;
          if (ij > i){
            unsigned long long a = sk[i], b = sk[ij];
            bool up = ((i & kk) == 0);
            if ((a > b) == up){ sk[i] = b; sk[ij] = a; }
          }
        }
        __syncthreads();
      }
    }

    const float inv65535 = 1.f/65535.f;
    uint32_t C = (K + 63) >> 6;
    uint32_t b0 = lane*C, e0 = min(b0 + C, K);
    float p = 1.f;
    for (uint32_t i=b0; i<e0; ++i){
      float a = (float)((uint32_t)(sk[i] >> 16) & 0xFFFFu) * inv65535;
      p *= (1.f - a);
    }
    float ip = p;
    #pragma unroll
    for (int d=1; d<64; d<<=1){ float v = __shfl_up(ip, d); if (lane >= d) ip *= v; }
    float T = __shfl_up(ip, 1);
    if (lane == 0) T = 1.f;

    float r_=0.f, g_=0.f, bl_=0.f, dpt_=0.f, acc_=0.f, nx_=0.f, ny_=0.f, nz_=0.f;
    for (uint32_t i=b0; i<e0; ++i){
      unsigned long long key = sk[i];
      float t = __uint_as_float((uint32_t)(key >> 32));
      float a = (float)((uint32_t)(key >> 16) & 0xFFFFu) * inv65535;
      uint32_t g = (uint32_t)(key & 0xFFFFu);
      float w = a * T;
      const float* gp = &geo[(size_t)g*16];
      const float* cp = &col[(size_t)g*3];
      r_  += w * cp[0]; g_ += w * cp[1]; bl_ += w * cp[2];
      dpt_ += w * t; acc_ += w;
      nx_ += w * gp[6]; ny_ += w * gp[7]; nz_ += w * gp[8];
      T *= (1.f - a);
    }
    comp_write(px, npix, lane, r_,g_,bl_,dpt_,acc_,nx_,ny_,nz_, bg, out);
    __syncthreads();   // protect sk reuse on next grid-stride iteration
  }
}

// ---------------- host launcher ----------------
extern "C" void kernel_launch(void* const* d_in, const int* in_sizes, int n_in,
                              void* d_out, int out_size, void* d_ws, size_t ws_size,
                              hipStream_t stream)
{
  const float* ray_o  = (const float*)d_in[0];
  const float* ray_d  = (const float*)d_in[1];
  const float* means  = (const float*)d_in[2];
  const float* scales = (const float*)d_in[3];
  const float* rot    = (const float*)d_in[4];
  const float* opac   = (const float*)d_in[5];
  const float* colors = (const float*)d_in[6];
  const float* bg     = (const float*)d_in[7];
  float* out = (float*)d_out;

  int npix = in_sizes[0] / 3;     // 16384
  int P    = in_sizes[2] / 3;     // 4096
  int W    = (int)(sqrtf((float)npix) + 0.5f);   // square image (reference H=W)
  int H    = npix / W;
  int TXB  = (W + TB - 1) / TB;
  int TYB  = (H + TB - 1) / TB;
  int NTB  = TXB * TYB;          // 64 for 128x128
  int STX  = (W + TS - 1) / TS;
  int STY  = (H + TS - 1) / TS;
  int NST  = STX * STY;          // 256 for 128x128

  int initN = npix > P ? npix : P;
  int nPrepBlocks = (initN + 255)/256;

  uint8_t* ws = (uint8_t*)d_ws;
  size_t o_geo   = 0;
  size_t sz_geo  = ((size_t)P*16*4 + 255) & ~(size_t)255;
  size_t o_col   = o_geo + sz_geo;
  size_t sz_col  = ((size_t)P*3*4 + 255) & ~(size_t)255;
  size_t o_bbox  = o_col + sz_col;
  size_t sz_bbox = ((size_t)P*16 + 255) & ~(size_t)255;
  size_t o_cnt   = o_bbox + sz_bbox;
  size_t sz_pix  = ((size_t)npix*4 + 255) & ~(size_t)255;
  size_t o_tlen  = o_cnt + sz_pix;
  size_t sz_ntb  = ((size_t)NTB*4 + 255) & ~(size_t)255;
  size_t o_bad   = o_tlen + sz_ntb;
  size_t sz_bad  = ((size_t)nPrepBlocks*4 + 255) & ~(size_t)255;
  size_t o_tlist = o_bad + sz_bad;
  size_t sz_tlist= (((size_t)NTB*(size_t)P*4) + 255) & ~(size_t)255;  // 1 MB @128
  size_t o_k64   = o_tlist + sz_tlist;                                // 8 MB

  float*    geo     = (float*)(ws + o_geo);
  float*    col     = (float*)(ws + o_col);
  int4*     bbox    = (int4*)(ws + o_bbox);
  uint32_t* cnt     = (uint32_t*)(ws + o_cnt);
  uint32_t* tileLen = (uint32_t*)(ws + o_tlen);
  uint32_t* badArr  = (uint32_t*)(ws + o_bad);
  uint32_t* tileList= (uint32_t*)(ws + o_tlist);
  unsigned long long* keys64 = (unsigned long long*)(ws + o_k64);

  k_prep<<<nPrepBlocks, 256, 0, stream>>>(rot, means, scales, opac, colors,
                                          ray_o, ray_d, geo, col, bbox, cnt,
                                          badArr, P, npix, W, H);
  if (NTB <= 1024){
    k_bin<<<1, 1024, 0, stream>>>(bbox, tileLen, tileList, badArr, nPrepBlocks,
                                  P, W, H, TXB, TYB);
  } else {
    k_fbfix<<<1, 1024, 0, stream>>>(bbox, badArr, nPrepBlocks, P, W, H);
    hipMemsetAsync(tileLen, 0, sz_ntb, stream);
    k_bin_global<<<(P + 255)/256, 256, 0, stream>>>(bbox, tileLen, tileList, P, TXB);
  }
  dim3 tgrid(NST, NSL);
  k_trace<<<tgrid, 64, 0, stream>>>(geo, bbox, ray_o, ray_d, tileLen, tileList,
                                    cnt, keys64, W, H, TXB, STX, P);
  k_comp_small<<<1024, 256, 0, stream>>>(keys64, cnt, geo, col, bg, out, npix);
  k_comp_over<<<1024, 64, 0, stream>>>(geo, bbox, col, ray_o, ray_d, tileLen, tileList,
                                       cnt, bg, out, npix, W, TXB, P);
}

// Round 16
// 121.727 us; speedup vs baseline: 1.5960x; 1.0897x over previous
//
#include <hip/hip_runtime.h>
#include <stdint.h>

#define NEAR_T  0.2f
#define SIG2MAX 9.0f
#define AMIN    (1.0f/255.0f)
#define NSL     8       // slices per sub-tile for the trace pass
#define TS      8       // trace sub-tile edge (8x8 = 64 px = one wave)
#define TB      16      // binning tile edge
#define KFIX    64      // fixed per-pixel key capacity (fast path)

__device__ __forceinline__ float dot3(float ax,float ay,float az,
                                      float bx,float by,float bz){
  return fmaf(ax,bx, fmaf(ay,by, az*bz));
}

__device__ __forceinline__ bool eval_hit(const float* __restrict__ gp,
    float rox,float roy,float roz, float rdx,float rdy,float rdz,
    float& t_out, float& a_out)
{
  float nx=gp[6], ny=gp[7], nz=gp[8];
  float den  = dot3(rdx,rdy,rdz, nx,ny,nz);
  float aden = fabsf(den);
  float num  = gp[11] - dot3(rox,roy,roz, nx,ny,nz);
  float sden = (aden < 1e-8f) ? 1e-8f : den;
  float t = __fdividef(num, sden);
  float ru = dot3(rox,roy,roz, gp[0],gp[1],gp[2]);
  float du = dot3(rdx,rdy,rdz, gp[0],gp[1],gp[2]);
  float u  = fmaf(t, du, ru - gp[9])  * gp[12];
  float rv = dot3(rox,roy,roz, gp[3],gp[4],gp[5]);
  float dv = dot3(rdx,rdy,rdz, gp[3],gp[4],gp[5]);
  float v  = fmaf(t, dv, rv - gp[10]) * gp[13];
  float r2 = fmaf(u,u, v*v);
  float G  = __expf(-0.5f*r2);
  float a  = fminf(gp[14]*G, 0.99f);
  t_out = t; a_out = a;
  return (t > NEAR_T) & (r2 < SIG2MAX) & (aden > 1e-8f) & (a > AMIN);
}

__device__ __forceinline__ unsigned long long make_key(float t, float a, uint32_t g){
  uint32_t a16 = (uint32_t)(a * 65535.f + 0.5f);
  return ((unsigned long long)__float_as_uint(t) << 32) |
         ((unsigned long long)a16 << 16) | (unsigned long long)g;
}

// pixel bbox (assumes pinhole map valid). Returns false if culled.
__device__ __forceinline__ bool pix_bbox_vals(
    float mx, float my, float mz, float ex, float ey, float ez,
    float axm, float bxm, float aym, float bym, int W, int H,
    int& x0, int& x1, int& y0, int& y1)
{
  float zmin=mz-ez, zmax=mz+ez;
  if (zmax <= 0.16f) return false;
  if (zmin <= 1e-3f){ x0=0; x1=W-1; y0=0; y1=H-1; return true; }
  float xmin=mx-ex, xmax=mx+ex, ymin=my-ey, ymax=my+ey;
  float gxmin = (xmin>=0.f)? xmin/zmax : xmin/zmin;
  float gxmax = (xmax>=0.f)? xmax/zmin : xmax/zmax;
  float gymin = (ymin>=0.f)? ymin/zmax : ymin/zmin;
  float gymax = (ymax>=0.f)? ymax/zmin : ymax/zmax;
  float p0 = (gxmin - bxm)/axm, p1 = (gxmax - bxm)/axm;
  float q0 = (gymin - bym)/aym, q1 = (gymax - bym)/aym;
  int ix0 = (int)floorf(fminf(p0,p1)) - 1;
  int ix1 = (int)ceilf (fmaxf(p0,p1)) + 1;
  int iy0 = (int)floorf(fminf(q0,q1)) - 1;
  int iy1 = (int)ceilf (fmaxf(q0,q1)) + 1;
  if (ix1 < 0 || ix0 > W-1 || iy1 < 0 || iy0 > H-1) return false;
  x0 = max(ix0,0); x1 = min(ix1,W-1);
  y0 = max(iy0,0); y1 = min(iy1,H-1);
  return true;
}

// ---------------- kernel 1: grid-wide prep + check + zero + bbox ----------------
// Flag protocol: every block writes badArr[blockIdx] unconditionally (no init).
__global__ __launch_bounds__(256)
void k_prep(const float* __restrict__ rot, const float* __restrict__ means,
            const float* __restrict__ scales, const float* __restrict__ opac,
            const float* __restrict__ colors, const float* __restrict__ ray_o,
            const float* __restrict__ ray_d,
            float* __restrict__ geo, float* __restrict__ col,
            int4* __restrict__ bbox, uint32_t* __restrict__ cnt,
            uint32_t* __restrict__ badArr, int P, int npix, int W, int H)
{
  __shared__ int sBad;
  int lt = threadIdx.x;
  if (lt == 0) sBad = 0;
  __syncthreads();
  int tid = blockIdx.x*blockDim.x + lt;
  float g0x = ray_d[0]/ray_d[2], g0y = ray_d[1]/ray_d[2];
  float axm = ray_d[3]/ray_d[5] - g0x;
  float aym = ray_d[(size_t)W*3+1]/ray_d[(size_t)W*3+2] - g0y;
  bool mapok = (fabsf(axm) > 1e-12f) && (fabsf(aym) > 1e-12f);
  if (!mapok) sBad = 1;
  if (tid < npix){
    cnt[tid] = 0u;
    int ix = tid % W, iy = tid / W;
    float rox=ray_o[tid*3+0], roy=ray_o[tid*3+1], roz=ray_o[tid*3+2];
    float rdx=ray_d[tid*3+0], rdy=ray_d[tid*3+1], rdz=ray_d[tid*3+2];
    bool ok = (rox==0.f) & (roy==0.f) & (roz==0.f) & (rdz > 0.8f);
    if (ok && mapok){
      float gx = rdx/rdz, gy = rdy/rdz;
      ok = (fabsf(gx - fmaf(axm,(float)ix,g0x)) <= 3e-4f) &
           (fabsf(gy - fmaf(aym,(float)iy,g0y)) <= 3e-4f);
    }
    if (!ok) sBad = 1;
  }
  if (tid < P){
    int g = tid;
    float qw=rot[g*4+0], qx=rot[g*4+1], qy=rot[g*4+2], qz=rot[g*4+3];
    float n = sqrtf(qw*qw+qx*qx+qy*qy+qz*qz) + 1e-12f;
    qw/=n; qx/=n; qy/=n; qz/=n;
    float tux = 1.f-2.f*(qy*qy+qz*qz), tuy = 2.f*(qx*qy+qw*qz), tuz = 2.f*(qx*qz-qw*qy);
    float tvx = 2.f*(qx*qy-qw*qz), tvy = 1.f-2.f*(qx*qx+qz*qz), tvz = 2.f*(qy*qz+qw*qx);
    float nx  = 2.f*(qx*qz+qw*qy), ny  = 2.f*(qy*qz-qw*qx), nz  = 1.f-2.f*(qx*qx+qy*qy);
    float mx=means[g*3+0], my=means[g*3+1], mz=means[g*3+2];
    float sx=scales[g*2+0], sy=scales[g*2+1];
    float* gp = &geo[(size_t)g*16];
    gp[0]=tux; gp[1]=tuy; gp[2]=tuz;
    gp[3]=tvx; gp[4]=tvy; gp[5]=tvz;
    gp[6]=nx;  gp[7]=ny;  gp[8]=nz;
    gp[9]  = mx*tux+my*tuy+mz*tuz;
    gp[10] = mx*tvx+my*tvy+mz*tvz;
    gp[11] = mx*nx +my*ny +mz*nz;
    gp[12] = 1.f/sx;
    gp[13] = 1.f/sy;
    gp[14] = opac[g];
    gp[15] = 0.f;
    col[g*3+0]=colors[g*3+0]; col[g*3+1]=colors[g*3+1]; col[g*3+2]=colors[g*3+2];
    const float R3 = 3.02f;
    float ex = R3*(sx*fabsf(tux)+sy*fabsf(tvx));
    float ey = R3*(sx*fabsf(tuy)+sy*fabsf(tvy));
    float ez = R3*(sx*fabsf(tuz)+sy*fabsf(tvz));
    int x0,x1,y0,y1;
    bool ok = mapok && pix_bbox_vals(mx,my,mz, ex,ey,ez, axm,g0x,aym,g0y, W,H,
                                     x0,x1,y0,y1);
    bbox[g] = ok ? make_int4(x0,x1,y0,y1) : make_int4(1,0,1,0);
  }
  __syncthreads();
  if (lt == 0) badArr[blockIdx.x] = (uint32_t)sBad;
}

// ---------------- kernel 2: per-tile binning (one block per 16x16 tile) --------
// Each block scans all P bboxes, appends matches into its own segment.
__global__ __launch_bounds__(256)
void k_bin_tile(const int4* __restrict__ bbox, uint32_t* __restrict__ tileLen,
                uint32_t* __restrict__ tileList, const uint32_t* __restrict__ badArr,
                uint32_t* __restrict__ fbFlag, int nb, int P, int TXB)
{
  __shared__ uint32_t sCnt;
  __shared__ int sFB;
  int t = blockIdx.x;
  int tid = threadIdx.x;
  if (tid == 0){ sCnt = 0u; sFB = 0; }
  __syncthreads();
  for (int i=tid; i<nb; i+=256) if (badArr[i] != 0u) sFB = 1;
  __syncthreads();
  bool fb = (sFB != 0);
  if (t == 0 && tid == 0) fbFlag[0] = fb ? 1u : 0u;
  int tx = t % TXB, ty = t / TXB;
  int x0t = tx*TB, x1t = x0t + TB-1;
  int y0t = ty*TB, y1t = y0t + TB-1;
  for (int g=tid; g<P; g+=256){
    int4 bb = bbox[g];
    bool match = fb || ((bb.x <= bb.y) &&
                 !(bb.x > x1t || bb.y < x0t || bb.z > y1t || bb.w < y0t));
    if (match){
      uint32_t slot = atomicAdd(&sCnt, 1u);
      tileList[(size_t)t*P + slot] = (uint32_t)g;
    }
  }
  __syncthreads();
  if (tid == 0) tileLen[t] = sCnt;
}

// ---------------- kernel 3: trace, one wave per 8x8 sub-tile slice -------------
__global__ __launch_bounds__(64)
void k_trace(const float* __restrict__ geo, const int4* __restrict__ bbox,
             const float* __restrict__ ray_o, const float* __restrict__ ray_d,
             const uint32_t* __restrict__ tileLen, const uint32_t* __restrict__ tileList,
             const uint32_t* __restrict__ fbFlag, uint32_t* __restrict__ cnt,
             unsigned long long* __restrict__ keys64,
             int W, int H, int TXB, int STX, int P)
{
  int st = blockIdx.x;
  int stx = st % STX, sty = st / STX;
  int lane = threadIdx.x;
  int ix = stx*TS + (lane & (TS-1));
  int iy = sty*TS + (lane / TS);
  bool live = (ix < W) & (iy < H);
  int px = live ? (iy*W + ix) : 0;
  int pt = (sty*TS/TB)*TXB + (stx*TS/TB);
  uint32_t base = (uint32_t)pt * (uint32_t)P;
  uint32_t len  = tileLen[pt];
  bool fb = (fbFlag[0] != 0u);
  int sx0 = stx*TS, sx1 = sx0 + TS-1;
  int sy0 = sty*TS, sy1 = sy0 + TS-1;
  float rox=ray_o[px*3+0], roy=ray_o[px*3+1], roz=ray_o[px*3+2];
  float rdx=ray_d[px*3+0], rdy=ray_d[px*3+1], rdz=ray_d[px*3+2];
  for (uint32_t s = blockIdx.y; s < len; s += NSL){
    int gu = __builtin_amdgcn_readfirstlane((int)tileList[base+s]);
    if (!fb){
      int4 bb = bbox[gu];
      if (bb.x > sx1 || bb.y < sx0 || bb.z > sy1 || bb.w < sy0) continue;  // uniform
    }
    const float* gp = &geo[(size_t)gu*16];
    float t,a;
    bool hit = eval_hit(gp, rox,roy,roz, rdx,rdy,rdz, t, a) && live;
    if (hit){
      uint32_t slot = atomicAdd(&cnt[px], 1u);
      if (slot < KFIX) keys64[(size_t)px*KFIX + slot] = make_key(t, a, (uint32_t)gu);
    }
  }
}

// ---------------- composite helpers ----------------
__device__ __forceinline__ float wred(float v){
  #pragma unroll
  for (int d=32; d>0; d>>=1) v += __shfl_down(v, d);
  return v;
}

__device__ __forceinline__ void comp_write(int px, int npix, int lane,
    float r_, float g_, float bl_, float dpt_, float acc_,
    float nx_, float ny_, float nz_, const float* __restrict__ bg,
    float* __restrict__ out)
{
  r_ = wred(r_); g_ = wred(g_); bl_ = wred(bl_);
  dpt_ = wred(dpt_); acc_ = wred(acc_);
  nx_ = wred(nx_); ny_ = wred(ny_); nz_ = wred(nz_);
  if (lane == 0){
    float one_m = 1.f - acc_;
    out[(size_t)px*3+0] = r_  + one_m*bg[0];
    out[(size_t)px*3+1] = g_  + one_m*bg[1];
    out[(size_t)px*3+2] = bl_ + one_m*bg[2];
    out[(size_t)npix*3 + px] = dpt_;
    out[(size_t)npix*4 + px] = acc_;
    out[(size_t)npix*5 + (size_t)px*3+0] = nx_;
    out[(size_t)npix*5 + (size_t)px*3+1] = ny_;
    out[(size_t)npix*5 + (size_t)px*3+2] = nz_;
  }
}

// ---------------- kernel 4: merged composite --------------------------------
// All waves: in-register sort+composite for K<=KFIX pixels.
// Wave 0 of each block additionally handles rare overflow pixels via
// single-wave LDS bitonic re-trace (no __syncthreads -- one wave, in-order LDS).
__global__ __launch_bounds__(256)
void k_comp(const unsigned long long* __restrict__ keys64,
            const uint32_t* __restrict__ cnt,
            const float* __restrict__ geo, const int4* __restrict__ bbox,
            const float* __restrict__ col,
            const float* __restrict__ ray_o, const float* __restrict__ ray_d,
            const uint32_t* __restrict__ tileLen, const uint32_t* __restrict__ tileList,
            const uint32_t* __restrict__ fbFlag, const float* __restrict__ bg,
            float* __restrict__ out, int npix, int W, int TXB, int P)
{
  __shared__ unsigned long long sk[4096];   // used only by wave 0 overflow path
  int lane = threadIdx.x & 63;
  int wave = threadIdx.x >> 6;
  const float inv65535 = 1.f/65535.f;

  // ---- phase A: fast path (all waves) ----
  for (int px = (int)(blockIdx.x*4u + wave); px < npix; px += (int)(gridDim.x*4u)){
    uint32_t K = cnt[px];
    if (K > (uint32_t)KFIX) continue;
    unsigned long long key = (lane < (int)K) ? keys64[(size_t)px*KFIX + lane] : ~0ull;
    #pragma unroll
    for (int k=2; k<=64; k<<=1){
      #pragma unroll
      for (int j=k>>1; j>0; j>>=1){
        unsigned long long other = __shfl_xor(key, j);
        bool keep_min = (((lane & j) == 0) == ((lane & k) == 0));
        unsigned long long lo = key < other ? key : other;
        unsigned long long hi = key < other ? other : key;
        key = keep_min ? lo : hi;
      }
    }
    bool valid = lane < (int)K;
    float a = (float)((uint32_t)(key >> 16) & 0xFFFFu) * inv65535;
    float p = valid ? (1.f - a) : 1.f;
    float ip = p;
    #pragma unroll
    for (int d=1; d<64; d<<=1){ float v = __shfl_up(ip, d); if (lane >= d) ip *= v; }
    float T = __shfl_up(ip, 1);
    if (lane == 0) T = 1.f;
    float r_=0.f, g_=0.f, bl_=0.f, dpt_=0.f, acc_=0.f, nx_=0.f, ny_=0.f, nz_=0.f;
    if (valid){
      float t = __uint_as_float((uint32_t)(key >> 32));
      uint32_t g = (uint32_t)(key & 0xFFFFu);
      float w = a * T;
      const float* gp = &geo[(size_t)g*16];
      const float* cp = &col[(size_t)g*3];
      r_ = w*cp[0]; g_ = w*cp[1]; bl_ = w*cp[2];
      dpt_ = w*t; acc_ = w;
      nx_ = w*gp[6]; ny_ = w*gp[7]; nz_ = w*gp[8];
    }
    comp_write(px, npix, lane, r_,g_,bl_,dpt_,acc_,nx_,ny_,nz_, bg, out);
  }

  // ---- phase B: overflow path (wave 0 only; rare) ----
  if (wave != 0) return;
  bool fb = (fbFlag[0] != 0u);
  unsigned long long ltm = (1ull << lane) - 1ull;
  for (int px = (int)blockIdx.x; px < npix; px += (int)gridDim.x){
    if (cnt[px] <= (uint32_t)KFIX) continue;
    int ix = px % W, iy = px / W;
    int pt = (iy/TB)*TXB + (ix/TB);
    uint32_t base = (uint32_t)pt * (uint32_t)P;
    uint32_t len  = tileLen[pt];
    float rox=ray_o[px*3+0], roy=ray_o[px*3+1], roz=ray_o[px*3+2];
    float rdx=ray_d[px*3+0], rdy=ray_d[px*3+1], rdz=ray_d[px*3+2];

    uint32_t run = 0;
    for (uint32_t s0=0; s0<len; s0+=64){
      uint32_t s = s0 + (uint32_t)lane;
      bool act = s < len;
      uint32_t gu = act ? tileList[base+s] : 0u;
      float t=0.f, a=0.f;
      bool hit = false;
      if (act){
        int4 bb = bbox[gu];
        if (fb || (bb.x <= ix && ix <= bb.y && bb.z <= iy && iy <= bb.w))
          hit = eval_hit(&geo[(size_t)gu*16], rox,roy,roz, rdx,rdy,rdz, t, a);
      }
      unsigned long long m = __ballot(hit);
      if (hit){
        uint32_t slot = run + (uint32_t)__popcll(m & ltm);
        if (slot < 4096u) sk[slot] = make_key(t, a, gu);
      }
      run += (uint32_t)__popcll(m);
    }
    uint32_t K = min(run, 4096u);
    uint32_t N = 1; while (N < K) N <<= 1;
    for (uint32_t i=K+lane; i<N; i+=64) sk[i] = ~0ull;

    for (uint32_t kk=2; kk<=N; kk<<=1){
      for (uint32_t j=kk>>1; j>0; j>>=1){
        for (uint32_t i=lane; i<N; i+=64){
          uint32_t ij = i ^ j;
          if (ij > i){
            unsigned long long a = sk[i], b = sk[ij];
            bool up = ((i & kk) == 0);
            if ((a > b) == up){ sk[i] = b; sk[ij] = a; }
          }
        }
      }
    }

    uint32_t C = (K + 63) >> 6;
    uint32_t b0 = lane*C, e0 = min(b0 + C, K);
    float p = 1.f;
    for (uint32_t i=b0; i<e0; ++i){
      float a = (float)((uint32_t)(sk[i] >> 16) & 0xFFFFu) * inv65535;
      p *= (1.f - a);
    }
    float ip = p;
    #pragma unroll
    for (int d=1; d<64; d<<=1){ float v = __shfl_up(ip, d); if (lane >= d) ip *= v; }
    float T = __shfl_up(ip, 1);
    if (lane == 0) T = 1.f;

    float r_=0.f, g_=0.f, bl_=0.f, dpt_=0.f, acc_=0.f, nx_=0.f, ny_=0.f, nz_=0.f;
    for (uint32_t i=b0; i<e0; ++i){
      unsigned long long key = sk[i];
      float t = __uint_as_float((uint32_t)(key >> 32));
      float a = (float)((uint32_t)(key >> 16) & 0xFFFFu) * inv65535;
      uint32_t g = (uint32_t)(key & 0xFFFFu);
      float w = a * T;
      const float* gp = &geo[(size_t)g*16];
      const float* cp = &col[(size_t)g*3];
      r_  += w * cp[0]; g_ += w * cp[1]; bl_ += w * cp[2];
      dpt_ += w * t; acc_ += w;
      nx_ += w * gp[6]; ny_ += w * gp[7]; nz_ += w * gp[8];
      T *= (1.f - a);
    }
    comp_write(px, npix, lane, r_,g_,bl_,dpt_,acc_,nx_,ny_,nz_, bg, out);
  }
}

// ---------------- host launcher ----------------
extern "C" void kernel_launch(void* const* d_in, const int* in_sizes, int n_in,
                              void* d_out, int out_size, void* d_ws, size_t ws_size,
                              hipStream_t stream)
{
  const float* ray_o  = (const float*)d_in[0];
  const float* ray_d  = (const float*)d_in[1];
  const float* means  = (const float*)d_in[2];
  const float* scales = (const float*)d_in[3];
  const float* rot    = (const float*)d_in[4];
  const float* opac   = (const float*)d_in[5];
  const float* colors = (const float*)d_in[6];
  const float* bg     = (const float*)d_in[7];
  float* out = (float*)d_out;

  int npix = in_sizes[0] / 3;     // 16384
  int P    = in_sizes[2] / 3;     // 4096
  int W    = (int)(sqrtf((float)npix) + 0.5f);   // square image (reference H=W)
  int H    = npix / W;
  int TXB  = (W + TB - 1) / TB;
  int TYB  = (H + TB - 1) / TB;
  int NTB  = TXB * TYB;          // 64 for 128x128
  int STX  = (W + TS - 1) / TS;
  int STY  = (H + TS - 1) / TS;
  int NST  = STX * STY;          // 256 for 128x128

  int initN = npix > P ? npix : P;
  int nPrepBlocks = (initN + 255)/256;

  uint8_t* ws = (uint8_t*)d_ws;
  size_t o_geo   = 0;
  size_t sz_geo  = ((size_t)P*16*4 + 255) & ~(size_t)255;
  size_t o_col   = o_geo + sz_geo;
  size_t sz_col  = ((size_t)P*3*4 + 255) & ~(size_t)255;
  size_t o_bbox  = o_col + sz_col;
  size_t sz_bbox = ((size_t)P*16 + 255) & ~(size_t)255;
  size_t o_cnt   = o_bbox + sz_bbox;
  size_t sz_pix  = ((size_t)npix*4 + 255) & ~(size_t)255;
  size_t o_tlen  = o_cnt + sz_pix;
  size_t sz_ntb  = ((size_t)NTB*4 + 255) & ~(size_t)255;
  size_t o_fb    = o_tlen + sz_ntb;
  size_t o_bad   = o_fb + 256;
  size_t sz_bad  = ((size_t)nPrepBlocks*4 + 255) & ~(size_t)255;
  size_t o_tlist = o_bad + sz_bad;
  size_t sz_tlist= (((size_t)NTB*(size_t)P*4) + 255) & ~(size_t)255;  // 1 MB @128
  size_t o_k64   = o_tlist + sz_tlist;                                // 8 MB

  float*    geo     = (float*)(ws + o_geo);
  float*    col     = (float*)(ws + o_col);
  int4*     bbox    = (int4*)(ws + o_bbox);
  uint32_t* cnt     = (uint32_t*)(ws + o_cnt);
  uint32_t* tileLen = (uint32_t*)(ws + o_tlen);
  uint32_t* fbFlag  = (uint32_t*)(ws + o_fb);
  uint32_t* badArr  = (uint32_t*)(ws + o_bad);
  uint32_t* tileList= (uint32_t*)(ws + o_tlist);
  unsigned long long* keys64 = (unsigned long long*)(ws + o_k64);

  k_prep<<<nPrepBlocks, 256, 0, stream>>>(rot, means, scales, opac, colors,
                                          ray_o, ray_d, geo, col, bbox, cnt,
                                          badArr, P, npix, W, H);
  k_bin_tile<<<NTB, 256, 0, stream>>>(bbox, tileLen, tileList, badArr, fbFlag,
                                      nPrepBlocks, P, TXB);
  dim3 tgrid(NST, NSL);
  k_trace<<<tgrid, 64, 0, stream>>>(geo, bbox, ray_o, ray_d, tileLen, tileList,
                                    fbFlag, cnt, keys64, W, H, TXB, STX, P);
  k_comp<<<1024, 256, 0, stream>>>(keys64, cnt, geo, bbox, col, ray_o, ray_d,
                                   tileLen, tileList, fbFlag, bg, out,
                                   npix, W, TXB, P);
}